// Round 6
// baseline (342.902 us; speedup 1.0000x reference)
//
#include <hip/hip_runtime.h>

#define B_ 8
#define H_ 128
#define W_ 256
#define C_ 128
#define D_ 128
#define PS 136   // p_lds row stride in shorts (272 B -> bank offset +4/row, 2-way max = free)

typedef __attribute__((ext_vector_type(4))) float f32x4;
typedef __attribute__((ext_vector_type(8))) short s16x8;
typedef __attribute__((ext_vector_type(4))) unsigned short u16x4;

__device__ __forceinline__ unsigned short f2bf(float f) {
    union { float f; unsigned u; } v; v.f = f;
    unsigned r = v.u + 0x7fffu + ((v.u >> 16) & 1u);   // RNE
    return (unsigned short)(r >> 16);
}
__device__ __forceinline__ float bf2f(unsigned short u) {
    union { unsigned u; float f; } v; v.u = ((unsigned)u) << 16; return v.f;
}
__device__ __forceinline__ float relu(float v) { return fmaxf(v, 0.f); }

// ---------------------------------------------------------------- K0
// c1x[b,i,w] = b1 + sum_{k,c} x[b,i,w+k-4,c]*w1[k,c]  (raw, pre-relu)
// Round-6 rewrite: LDS-staged quarters. The old k0 read x with scalar 4B/lane
// loads (256B/instr) + 2x halo re-read -> est ~90us, the largest hidden kernel.
// Now: per quarter (64 outputs) stage the 72-row input window into LDS with
// coalesced f32x4 loads (1KB/instr), then run the EXACT same sliding-window
// FMA + shuffle-reduce reading from LDS. Out-of-range rows staged as 0.0f
// (adds exact +-0 -> bit-identical c1x, absmax preserved).
// s1[k] = sum_c w1[k,c]; w2t[d][c] = bf16(w2[0,4,c,d]); cs2[d] = sum_c w2[0,4,c,d]
__global__ __launch_bounds__(256, 3) void k0_conv1(
    const float* __restrict__ x, const float* __restrict__ w1,
    const float* __restrict__ b1, const float* __restrict__ w2,
    float* __restrict__ c1x, float* __restrict__ s1,
    unsigned short* __restrict__ w2t, float* __restrict__ cs2) {
    int bid = blockIdx.x, tid = threadIdx.x;
    if (bid >= B_ * H_) {                      // w2t staging blocks
        int idx = (bid - B_ * H_) * 256 + tid; // 0..16383
        int d = idx & (D_ - 1), c = idx >> 7;
        w2t[d * C_ + c] = f2bf(w2[4 * C_ * D_ + c * D_ + d]);
        if (bid == B_ * H_ && tid < D_) {      // cs2 column sums (fp32)
            float s = 0.f;
            for (int cc = 0; cc < C_; ++cc) s += w2[4 * C_ * D_ + cc * D_ + tid];
            cs2[tid] = s;
        }
        return;
    }
    if (bid == 0 && tid < 9) {
        float s = 0.f;
        for (int c = 0; c < C_; ++c) s += w1[tid * C_ + c];
        s1[tid] = s;
    }
    __shared__ float w1s[9 * C_];    // 4608 B
    __shared__ float xs[72 * C_];    // 36864 B  (quarter window: 64 outputs + 8 halo)
    for (int t = tid; t < 9 * C_; t += 256) w1s[t] = w1[t];
    __syncthreads();

    const float* xr = x + (size_t)bid * (W_ * C_);
    int wv = tid >> 6, l = tid & 63;
    float w1a[9], w1b[9];
#pragma unroll
    for (int k = 0; k < 9; ++k) { w1a[k] = w1s[k * C_ + l]; w1b[k] = w1s[k * C_ + l + 64]; }
    float b1v = b1[0];

    for (int qt = 0; qt < 4; ++qt) {
        int q0 = qt * 64 - 4;                  // global w of xs row 0
        // ---- stage quarter window: 72 rows x 128 c fp32, coalesced f32x4
#pragma unroll
        for (int it = 0; it < 9; ++it) {
            int t2 = it * 256 + tid;           // f32x4 index, 0..2303
            int r = t2 >> 5;                   // local row (4*t2/128)
            int c = (t2 & 31) * 4;
            int w = q0 + r;
            f32x4 v = (w >= 0 && w < W_) ? *(const f32x4*)(xr + w * C_ + c)
                                         : (f32x4){0.f, 0.f, 0.f, 0.f};
            *(f32x4*)(&xs[r * C_ + c]) = v;
        }
        __syncthreads();
        // ---- compute: wave wv owns outputs [qt*64 + wv*16, +16) = 2 chunks of 8
#pragma unroll
        for (int ch = 0; ch < 2; ++ch) {
            int p0 = qt * 64 + wv * 16 + ch * 8;
            float part[8] = {0.f,0.f,0.f,0.f,0.f,0.f,0.f,0.f};
#pragma unroll
            for (int wr = 0; wr < 16; ++wr) {
                int rr = wv * 16 + ch * 8 + wr;        // = p0 + wr - 4 - q0, in [0,72)
                float v0 = xs[rr * C_ + l], v1 = xs[rr * C_ + l + 64];
#pragma unroll
                for (int pi = 0; pi < 8; ++pi) {
                    int k = wr - pi;
                    if (k >= 0 && k < 9) part[pi] += v0 * w1a[k] + v1 * w1b[k];
                }
            }
#pragma unroll
            for (int pi = 0; pi < 8; ++pi) {
                float v = part[pi];
#pragma unroll
                for (int off = 32; off > 0; off >>= 1) v += __shfl_down(v, off, 64);
                if (l == 0) c1x[(size_t)bid * W_ + p0 + pi] = v + b1v;
            }
        }
        __syncthreads();   // all reads done before next quarter's staging
    }
}

// ---------------------------------------------------------------- K12 (fused K1+K2)
// UNCHANGED from round 5 (control for this round).
// z-row read directly from x (clean lines, L3-resident), reg-staged with inline
// f2bf into p_lds; z and p share the buffer in place. sc[w] from c1x;
// GEMM1: v = relu(z@W2 + sc*cs2 + b2) [rank-1 sc fold];
// p[w+1] = z[w+1] + sc[w+1] + v[w]; GEMM2 on p; q epilogue.
__global__ __launch_bounds__(256, 2) void k12_fused(
    const float* __restrict__ x, const float* __restrict__ b2,
    const float* __restrict__ c1x_all, const float* __restrict__ s1,
    const unsigned short* __restrict__ w2t, const float* __restrict__ cs2,
    float* __restrict__ qout) {
    __shared__ unsigned short p_lds[W_ * PS];   // 69632 B (z, then p, in place)
    __shared__ float sc[W_];                    // 1024 B
    int bid = blockIdx.x;            // row index b*H + i
    int b = bid >> 7, i = bid & 127;
    int tid = threadIdx.x;
    const float* c1 = c1x_all + (size_t)b * H_ * W_;

    int rowY;
    if (i == H_ - 1) rowY = H_ - 1;
    else if (i <= H_ - 3) rowY = (i - 1) & (H_ - 1);
    else rowY = H_ - 2;

    const float* zrow = x + ((size_t)b * H_ + rowY) * (W_ * C_);
    float* qrow = qout + (size_t)bid * (W_ * C_);

    // ---- phase -1: reg-stage z row (fp32 -> bf16) into p_lds.
    {
        const f32x4* z4 = (const f32x4*)zrow;
#pragma unroll 4
        for (int it = 0; it < 32; ++it) {
            int g = it * 1024 + tid * 4;
            f32x4 v = z4[g >> 2];
            u16x4 o;
#pragma unroll
            for (int j = 0; j < 4; ++j) o[j] = f2bf(v[j]);
            int row = g >> 7, col = g & 127;
            *(u16x4*)(&p_lds[row * PS + col]) = o;
        }
    }

    {   // phase 0: per-w scalar sc
        int w = tid;
        float scv;
        if (i == H_ - 1) {
            scv = relu(c1[(H_ - 2) * W_ + w]);
        } else {
            int iu = (i <= H_ - 3) ? i : (H_ - 1);
            float cu = c1[iu * W_ + w];
            if (iu >= 1) {
                const float* tp = c1 + (iu - 1) * W_;
#pragma unroll
                for (int k = 0; k < 9; ++k) {
                    int wk = w + k - 4;
                    if (wk >= 0 && wk < W_) cu += relu(tp[wk]) * s1[k];
                }
            }
            float tY = (rowY >= 1) ? relu(c1[(rowY - 1) * W_ + w]) : 0.f;
            scv = tY + relu(cu);
        }
        sc[w] = scv;
    }
    __syncthreads();   // staged z visible; sc visible

    int wv = tid >> 6, l = tid & 63, q = l >> 4, l15 = l & 15;
    int m0 = wv * 64;

    // epilogue constants: 4 consecutive channels per thread per nt
    f32x4 b2v4[8], cs2v4[8];
#pragma unroll
    for (int nt = 0; nt < 8; ++nt) {
        int d0 = nt * 16 + q * 4;
        b2v4[nt] = *(const f32x4*)(b2 + d0);
        cs2v4[nt] = *(const f32x4*)(cs2 + d0);
    }

    f32x4 acc[4][8];
#pragma unroll
    for (int mt = 0; mt < 4; ++mt)
#pragma unroll
        for (int nt = 0; nt < 8; ++nt) acc[mt][nt] = (f32x4){0.f, 0.f, 0.f, 0.f};

    // ---- GEMM1: A-op = w2t frag, B-op = z frag (bf16, LDS)  -> D[d, w]
#pragma unroll
    for (int kk = 0; kk < C_; kk += 32) {
        s16x8 af[4], bfr[8];
#pragma unroll
        for (int mt = 0; mt < 4; ++mt) {
            int w = m0 + mt * 16 + l15;
            af[mt] = *(const s16x8*)(&p_lds[w * PS + kk + q * 8]);   // staged z
        }
#pragma unroll
        for (int nt = 0; nt < 8; ++nt)
            bfr[nt] = *(const s16x8*)(w2t + (nt * 16 + l15) * C_ + kk + q * 8);
#pragma unroll
        for (int mt = 0; mt < 4; ++mt)
#pragma unroll
            for (int nt = 0; nt < 8; ++nt)
                acc[mt][nt] = __builtin_amdgcn_mfma_f32_16x16x32_bf16(bfr[nt], af[mt], acc[mt][nt], 0, 0, 0);
    }
    __syncthreads();   // all waves done reading z before in-place p overwrite

    // ---- epilogue 1: p[w+1] = z[w+1] + sc[w+1] + v[w]  (in-place LDS update)
#pragma unroll
    for (int mt = 0; mt < 4; ++mt) {
        int w = m0 + mt * 16 + l15;
        if (w < W_ - 1) {
            float scw = sc[w], scw1 = sc[w + 1];
#pragma unroll
            for (int nt = 0; nt < 8; ++nt) {
                int d0 = nt * 16 + q * 4;
                u16x4 zv4 = *(const u16x4*)(&p_lds[(w + 1) * PS + d0]);
                u16x4 pb;
                f32x4 pf;
#pragma unroll
                for (int r = 0; r < 4; ++r) {
                    float v = relu(acc[mt][nt][r] + scw * cs2v4[nt][r] + b2v4[nt][r]);
                    float p = bf2f(zv4[r]) + scw1 + v;
                    pf[r] = p;
                    pb[r] = f2bf(p);
                }
                *(u16x4*)(&p_lds[(w + 1) * PS + d0]) = pb;       // ds_write_b64
                if (w == W_ - 2)                                  // q[W-1] = p[W-1], exact fp32
                    *(f32x4*)(qrow + (W_ - 1) * C_ + d0) = pf;
            }
        }
    }
    // p[0] = z[0] + sc[0]: row 0 still holds z[0]; same-thread read-then-write
    if (tid < C_) {
        float z0 = bf2f(p_lds[tid]);
        p_lds[tid] = f2bf(z0 + sc[0]);
    }
    __syncthreads();

    // ---- GEMM2: A-op = w2t frag, B-op = p frag (bf16, LDS)
#pragma unroll
    for (int mt = 0; mt < 4; ++mt)
#pragma unroll
        for (int nt = 0; nt < 8; ++nt) acc[mt][nt] = (f32x4){0.f, 0.f, 0.f, 0.f};
#pragma unroll
    for (int kk = 0; kk < C_; kk += 32) {
        s16x8 af[4], bfr[8];
#pragma unroll
        for (int mt = 0; mt < 4; ++mt) {
            int w = m0 + mt * 16 + l15;
            af[mt] = *(const s16x8*)(&p_lds[w * PS + kk + q * 8]);
        }
#pragma unroll
        for (int nt = 0; nt < 8; ++nt)
            bfr[nt] = *(const s16x8*)(w2t + (nt * 16 + l15) * C_ + kk + q * 8);
#pragma unroll
        for (int mt = 0; mt < 4; ++mt)
#pragma unroll
            for (int nt = 0; nt < 8; ++nt)
                acc[mt][nt] = __builtin_amdgcn_mfma_f32_16x16x32_bf16(bfr[nt], af[mt], acc[mt][nt], 0, 0, 0);
    }
    // ---- epilogue 2: q stores (f32x4, 16B per lane)
#pragma unroll
    for (int mt = 0; mt < 4; ++mt) {
        int w = m0 + mt * 16 + l15;
        if (w == W_ - 2) continue;       // r[W-2] unused; q[W-1] already stored
        int wsrc = (w - 1) & (W_ - 1);
        int wd = (w <= W_ - 3) ? w : (W_ - 2);   // w==W-1 -> q[W-2] = r[W-1] + p[W-2]
#pragma unroll
        for (int nt = 0; nt < 8; ++nt) {
            int d0 = nt * 16 + q * 4;
            u16x4 pv4 = *(const u16x4*)(&p_lds[wsrc * PS + d0]);  // ds_read_b64
            f32x4 o;
#pragma unroll
            for (int r = 0; r < 4; ++r) {
                float rr = relu(acc[mt][nt][r] + b2v4[nt][r]);
                o[r] = rr + bf2f(pv4[r]);
            }
            *(f32x4*)(qrow + wd * C_ + d0) = o;
        }
    }
}

extern "C" void kernel_launch(void* const* d_in, const int* in_sizes, int n_in,
                              void* d_out, int out_size, void* d_ws, size_t ws_size,
                              hipStream_t stream) {
    const float* x  = (const float*)d_in[0];
    const float* w1 = (const float*)d_in[1];
    const float* b1 = (const float*)d_in[2];
    const float* w2 = (const float*)d_in[3];
    const float* b2 = (const float*)d_in[4];
    float* out = (float*)d_out;

    float* wsf = (float*)d_ws;
    // ws layout (floats): c1x[262144] | s1[16] | w2t[8192] | cs2[128]
    float* c1x = wsf;
    float* s1  = wsf + 262144;
    unsigned short* w2t = (unsigned short*)(wsf + 262160);
    float* cs2 = wsf + 270352;

    k0_conv1<<<B_ * H_ + (C_ * D_) / 256, 256, 0, stream>>>(x, w1, b1, w2, c1x, s1, w2t, cs2);
    k12_fused<<<B_ * H_, 256, 0, stream>>>(x, b2, c1x, s1, w2t, cs2, out);
}